// Round 3
// baseline (483.108 us; speedup 1.0000x reference)
//
#include <hip/hip_runtime.h>
#include <hip/hip_bf16.h>
#include <stdint.h>

typedef __hip_bfloat16 bf16;

#define VOCABN 100000
#define EDIM 128
#define BN 16
#define SN 2048
#define NCH 16   // s-chunks for u-update partials

// ---------- threefry2x32 (JAX-compatible, 20 rounds) ----------
__host__ __device__ inline void tf2x32(uint32_t k0, uint32_t k1,
                                       uint32_t x0, uint32_t x1,
                                       uint32_t* o0, uint32_t* o1) {
  const uint32_t rotA[4] = {13u, 15u, 26u, 6u};
  const uint32_t rotB[4] = {17u, 29u, 16u, 24u};
  uint32_t ks0 = k0, ks1 = k1, ks2 = k0 ^ k1 ^ 0x1BD11BDAu;
  x0 += ks0; x1 += ks1;
#pragma unroll
  for (int g = 0; g < 5; ++g) {
    const uint32_t* r = (g & 1) ? rotB : rotA;
#pragma unroll
    for (int i = 0; i < 4; ++i) {
      x0 += x1;
      x1 = (x1 << r[i]) | (x1 >> (32u - r[i]));
      x1 ^= x0;
    }
    uint32_t a0 = (g % 3 == 0) ? ks1 : ((g % 3 == 1) ? ks2 : ks0);
    uint32_t a1 = (g % 3 == 0) ? ks2 : ((g % 3 == 1) ? ks0 : ks1);
    x0 += a0;
    x1 += a1 + (uint32_t)(g + 1);
  }
  *o0 = x0; *o1 = x1;
}

// bf16 pair pack/unpack (elem0 = low 16 bits)
__device__ inline float blo(uint32_t v) { return __uint_as_float(v << 16); }
__device__ inline float bhi(uint32_t v) { return __uint_as_float(v & 0xffff0000u); }
__device__ inline uint16_t f2bu(float f) {
  bf16 h = __float2bfloat16(f);
  uint16_t u; __builtin_memcpy(&u, &h, 2); return u;
}

// ---------- h = hidden @ Wm^T + Wb ; also u = h ----------
__global__ void k_h(const float* __restrict__ hidden, const float* __restrict__ Wm,
                    const float* __restrict__ Wb, float* __restrict__ h,
                    float* __restrict__ u) {
  int b = blockIdx.x, j = threadIdx.x;
  __shared__ float hs[EDIM];
  hs[j] = hidden[b * EDIM + j];
  __syncthreads();
  const float4* w = (const float4*)(Wm + (size_t)j * EDIM);
  float acc = Wb[j];
#pragma unroll
  for (int i = 0; i < 32; ++i) {
    float4 v = w[i];
    acc += hs[4 * i] * v.x + hs[4 * i + 1] * v.y +
           hs[4 * i + 2] * v.z + hs[4 * i + 3] * v.w;
  }
  h[b * EDIM + j] = acc;
  u[b * EDIM + j] = acc;
}

// ---------- head: logits = h @ W^T + b ; gumbel-hard one-hot (f32 outputs) ----------
__global__ void k_head(const float* __restrict__ h, const float* __restrict__ W,
                       const float* __restrict__ bias, float* __restrict__ out_logit,
                       float* __restrict__ out_action, int N,
                       uint32_t k0, uint32_t k1) {
  int b = blockIdx.x, tid = threadIdx.x;
  __shared__ float hs[EDIM];
  __shared__ float sv[256];
  __shared__ int si[256];
  if (tid < EDIM) hs[tid] = h[b * EDIM + tid];
  __syncthreads();
  float best = -INFINITY; int bidx = 0x7FFFFFFF;
  for (int c = tid; c < N; c += 256) {
    const float4* w4 = (const float4*)(W + (size_t)c * EDIM);
    float acc = bias[c];
#pragma unroll
    for (int i = 0; i < 32; ++i) {
      float4 v = w4[i];
      acc += hs[4 * i] * v.x + hs[4 * i + 1] * v.y +
             hs[4 * i + 2] * v.z + hs[4 * i + 3] * v.w;
    }
    out_logit[(size_t)b * N + c] = acc;
    // gumbel noise, JAX partitionable threefry: bits = o0 ^ o1 of block(key,(0,flat))
    uint32_t o0, o1;
    tf2x32(k0, k1, 0u, (uint32_t)(b * N + c), &o0, &o1);
    uint32_t bits = o0 ^ o1;
    float u0 = __uint_as_float((bits >> 9) | 0x3f800000u) - 1.0f;
    float uu = fmaxf(1e-10f, u0 + 1e-10f);
    float g = -logf(-logf(uu));
    float z = acc + g;
    if (z > best) { best = z; bidx = c; }
  }
  sv[tid] = best; si[tid] = bidx;
  __syncthreads();
  for (int s = 128; s > 0; s >>= 1) {
    if (tid < s) {
      if (sv[tid + s] > sv[tid] ||
          (sv[tid + s] == sv[tid] && si[tid + s] < si[tid])) {
        sv[tid] = sv[tid + s]; si[tid] = si[tid + s];
      }
    }
    __syncthreads();
  }
  int arg = si[0];
  for (int c = tid; c < N; c += 256)
    out_action[(size_t)b * N + c] = (c == arg ? 1.0f : 0.0f);
}

// ---------- gather: G[t][b][s][e] = sum_m C[t][story[b,s,m]][e]  (t=0..2) ----------
__global__ void k_gather(const int* __restrict__ story, const float* __restrict__ C,
                         uint32_t* __restrict__ G) {
  int wid = (blockIdx.x << 2) | (threadIdx.x >> 6);  // (t, b*S+s)
  int lane = threadIdx.x & 63;
  int t = wid / (BN * SN);
  int bs = wid % (BN * SN);
  int4 idx = ((const int4*)story)[bs];
  const float2* r0 = (const float2*)(C + ((size_t)t * VOCABN + idx.x) * EDIM);
  const float2* r1 = (const float2*)(C + ((size_t)t * VOCABN + idx.y) * EDIM);
  const float2* r2 = (const float2*)(C + ((size_t)t * VOCABN + idx.z) * EDIM);
  const float2* r3 = (const float2*)(C + ((size_t)t * VOCABN + idx.w) * EDIM);
  float2 a = r0[lane], b = r1[lane], c = r2[lane], d = r3[lane];
  float lo = a.x + b.x + c.x + d.x;
  float hi = a.y + b.y + c.y + d.y;
  uint32_t packed = (uint32_t)f2bu(lo) | ((uint32_t)f2bu(hi) << 16);
  G[(size_t)wid * 64 + lane] = packed;
}

// ---------- logits: l[b,s] = sum_e G_t[b,s,e] * u[b,e] ----------
__global__ void k_logits(const uint32_t* __restrict__ Gt, const float* __restrict__ u,
                         float* __restrict__ l) {
  int wid = (blockIdx.x << 2) | (threadIdx.x >> 6);  // b*S+s
  int lane = threadIdx.x & 63;
  int b = wid >> 11;
  uint32_t v = Gt[(size_t)wid * 64 + lane];
  float2 uu = ((const float2*)(u + b * EDIM))[lane];
  float part = blo(v) * uu.x + bhi(v) * uu.y;
#pragma unroll
  for (int off = 32; off > 0; off >>= 1) part += __shfl_xor(part, off, 64);
  if (lane == 0) l[wid] = part;
}

// ---------- softmax over S per batch row ----------
__global__ void k_softmax(const float* __restrict__ l, float* __restrict__ p) {
  int b = blockIdx.x, tid = threadIdx.x;
  __shared__ float red[256];
  const float* lb = l + b * SN;
  float* pb = p + b * SN;
  float m = -INFINITY;
  for (int s = tid; s < SN; s += 256) m = fmaxf(m, lb[s]);
  red[tid] = m; __syncthreads();
  for (int s = 128; s > 0; s >>= 1) {
    if (tid < s) red[tid] = fmaxf(red[tid], red[tid + s]);
    __syncthreads();
  }
  m = red[0]; __syncthreads();
  float sum = 0.0f;
  for (int s = tid; s < SN; s += 256) {
    float e = expf(lb[s] - m);
    pb[s] = e; sum += e;
  }
  red[tid] = sum; __syncthreads();
  for (int s = 128; s > 0; s >>= 1) {
    if (tid < s) red[tid] += red[tid + s];
    __syncthreads();
  }
  float inv = 1.0f / red[0];
  for (int s = tid; s < SN; s += 256) pb[s] *= inv;
}

// ---------- u-update partials: part[b,ch,e] = sum_{s in chunk} G[b,s,e]*p[b,s] ----------
__global__ void k_upartial(const uint32_t* __restrict__ Gt, const float* __restrict__ p,
                           float* __restrict__ part) {
  int b = blockIdx.x >> 4;
  int ch = blockIdx.x & 15;
  int w = threadIdx.x >> 6, lane = threadIdx.x & 63;
  __shared__ float ps[128];
  __shared__ float acc_s[4][EDIM];
  if (threadIdx.x < 128) ps[threadIdx.x] = p[b * SN + ch * 128 + threadIdx.x];
  __syncthreads();
  float ax = 0.0f, ay = 0.0f;
  for (int s = w; s < 128; s += 4) {
    uint32_t v = Gt[((size_t)(b * SN + ch * 128 + s)) * 64 + lane];
    float pp = ps[s];
    ax += blo(v) * pp; ay += bhi(v) * pp;
  }
  acc_s[w][2 * lane] = ax; acc_s[w][2 * lane + 1] = ay;
  __syncthreads();
  if (threadIdx.x < EDIM) {
    float r = acc_s[0][threadIdx.x] + acc_s[1][threadIdx.x] +
              acc_s[2][threadIdx.x] + acc_s[3][threadIdx.x];
    part[(size_t)(b * NCH + ch) * EDIM + threadIdx.x] = r;
  }
}

__global__ void k_ureduce(const float* __restrict__ part, float* __restrict__ u) {
  int b = blockIdx.x, e = threadIdx.x;
  float r = 0.0f;
#pragma unroll
  for (int ch = 0; ch < NCH; ++ch) r += part[(size_t)(b * NCH + ch) * EDIM + e];
  u[b * EDIM + e] += r;
}

// ---------- final: masked sigmoid (f32 output) ----------
__global__ void k_final(const float* __restrict__ l, const int* __restrict__ lengths,
                        float* __restrict__ out) {
  int i = blockIdx.x * 256 + threadIdx.x;
  int b = i >> 11, s = i & 2047;
  float v = l[i];
  float r = (s < lengths[b]) ? 1.0f / (1.0f + expf(-v)) : 0.0f;
  out[i] = r;
}

extern "C" void kernel_launch(void* const* d_in, const int* in_sizes, int n_in,
                              void* d_out, int out_size, void* d_ws, size_t ws_size,
                              hipStream_t stream) {
  // Bind inputs by UNIQUE flat size (defensive against ordering assumptions).
  const int *story = nullptr, *lengths = nullptr;
  const float *hidden = nullptr, *C = nullptr, *Wm = nullptr, *Wb = nullptr,
              *W1w = nullptr, *W1b = nullptr, *W3w = nullptr, *W3b = nullptr,
              *W4w = nullptr, *W4b = nullptr;
  for (int i = 0; i < n_in; ++i) {
    switch (in_sizes[i]) {
      case 16 * 2048 * 4:     story   = (const int*)d_in[i]; break;
      case 16:                lengths = (const int*)d_in[i]; break;
      case 16 * 128:          hidden  = (const float*)d_in[i]; break;
      case 4 * 100000 * 128:  C       = (const float*)d_in[i]; break;
      case 128 * 128:         Wm      = (const float*)d_in[i]; break;
      case 128:               Wb      = (const float*)d_in[i]; break;
      case 2 * 128:           W1w     = (const float*)d_in[i]; break;
      case 2:                 W1b     = (const float*)d_in[i]; break;
      case 4000 * 128:        W3w     = (const float*)d_in[i]; break;
      case 4000:              W3b     = (const float*)d_in[i]; break;
      case 200 * 128:         W4w     = (const float*)d_in[i]; break;
      case 200:               W4b     = (const float*)d_in[i]; break;
      default: break;  // global_pointer (32768), is_decoding (1) unused
    }
  }
  float* out = (float*)d_out;

  float* ws   = (float*)d_ws;
  float* h    = ws;                       // 2048
  float* u    = ws + 2048;                // 2048
  float* l    = ws + 4096;                // 32768
  float* p    = l + BN * SN;              // 32768
  float* part = p + BN * SN;              // 32768
  uint32_t* G = (uint32_t*)(part + BN * NCH * EDIM);  // 3 * 16*2048*64 uints (bf16x2)

  // JAX: gkey = key(42); k1,k2,k3 = split(gkey,3)  [partitionable: key_i = block(key,(0,i))]
  uint32_t k1a, k1b, k2a, k2b, k3a, k3b;
  tf2x32(0u, 42u, 0u, 0u, &k1a, &k1b);
  tf2x32(0u, 42u, 0u, 1u, &k2a, &k2b);
  tf2x32(0u, 42u, 0u, 2u, &k3a, &k3b);

  // output offsets: sp 0, sp_act 32, qh 64, qh_act 64064, qt 128064, qt_act 131264, masked 134464
  k_h<<<BN, 128, 0, stream>>>(hidden, Wm, Wb, h, u);
  k_head<<<BN, 256, 0, stream>>>(h, W1w, W1b, out + 0,      out + 32,     2,    k1a, k1b);
  k_head<<<BN, 256, 0, stream>>>(h, W3w, W3b, out + 64,     out + 64064,  4000, k2a, k2b);
  k_head<<<BN, 256, 0, stream>>>(h, W4w, W4b, out + 128064, out + 131264, 200,  k3a, k3b);
  k_gather<<<3 * BN * SN / 4, 256, 0, stream>>>(story, C, G);
  for (int hop = 0; hop < 3; ++hop) {
    const uint32_t* Gt = G + (size_t)hop * BN * SN * 64;
    k_logits<<<BN * SN / 4, 256, 0, stream>>>(Gt, u, l);
    if (hop < 2) {
      k_softmax<<<BN, 256, 0, stream>>>(l, p);
      const uint32_t* Gn = G + (size_t)(hop + 1) * BN * SN * 64;
      k_upartial<<<BN * NCH, 256, 0, stream>>>(Gn, p, part);
      k_ureduce<<<BN, EDIM, 0, stream>>>(part, u);
    }
  }
  k_final<<<BN * SN / 256, 256, 0, stream>>>(l, lengths, out + 134464);
}